// Round 9
// baseline (645.437 us; speedup 1.0000x reference)
//
#include <hip/hip_runtime.h>

#define DIM   4096
#define KVDIM 1024   // n_kv_heads * head_dim
#define NB    8      // batch
#define TOTAL 16384
#define GRID2 1024   // 4 blocks/CU -> co-resident (VGPR<=64, 8.5 KB LDS)

// ---- kernel 1: up-projection (R6-proven) + zero the 16 column counters ----
__global__ __launch_bounds__(256)
void k_up(const float* __restrict__ emb, const float* __restrict__ wup,
          float* __restrict__ x, int* __restrict__ cnt) {
    if (blockIdx.x == 0 && threadIdx.x < 16) cnt[threadIdx.x] = 0;
    int wid  = blockIdx.x * 4 + (threadIdx.x >> 6);
    int lane = threadIdx.x & 63;
    int j = wid >> 3;      // 0..1023
    int b = wid & 7;
    const float4* e = (const float4*)(emb + b * DIM);
    const float4* w = (const float4*)(wup + (long)j * DIM);
    float acc = 0.f;
    #pragma unroll
    for (int ii = 0; ii < 16; ii++) {
        int it = ii * 64 + lane;
        float4 ev = e[it], wv = w[it];
        acc += ev.x * wv.x + ev.y * wv.y + ev.z * wv.z + ev.w * wv.w;
    }
    #pragma unroll
    for (int off = 32; off; off >>= 1) acc += __shfl_down(acc, off, 64);
    if (lane == 0) x[b * KVDIM + j] = acc;
}

// ---- kernel 2: fused down-projection + ragged broadcast (producer/consumer) --
// Block B: produce y columns o=4B..4B+3 (R6 K-split body), release-add 4 to
// cnt[B>>6]; then consume 4 out-tiles (cols [ct*256,+256), rows [rt*64,+64))
// after acquiring cnt[ct]==256. ct==B>>6 for both halves; all 1024 blocks
// co-resident -> spins always make progress.
__global__ __launch_bounds__(256)
void k_dc(const float* __restrict__ x, const float* __restrict__ wdn,
          float* __restrict__ y, int* __restrict__ cnt,
          const int* __restrict__ seqlen, float4* __restrict__ out) {
    __shared__ float4 tile[NB][65];   // consumer stage: 8 seq-rows x 64 float4 (pad)
    __shared__ float  part[4][NB];    // producer cross-wave partials
    const int B    = blockIdx.x;
    const int t    = threadIdx.x;
    const int wv   = t >> 6;
    const int lane = t & 63;

    // ================= produce: y[b, 4B+i] for b=0..7, i=0..3 =================
    #pragma unroll
    for (int i = 0; i < 4; i++) {
        const int o = B * 4 + i;
        const float4* w = (const float4*)(wdn + (long)o * DIM);
        float acc[NB];
        #pragma unroll
        for (int b = 0; b < NB; b++) acc[b] = 0.f;
        #pragma unroll
        for (int ii = 0; ii < 4; ii++) {
            int it = wv * 256 + ii * 64 + lane;       // float4 index in W_down row
            int k0 = it * 4;
            int kv = ((k0 >> 9) << 7) + (k0 & 127);   // repeat-interleave gather
            float4 wvv = w[it];
            #pragma unroll
            for (int b = 0; b < NB; b++) {
                const float4 xv = *(const float4*)(x + b * KVDIM + kv);
                acc[b] += xv.x * wvv.x + xv.y * wvv.y + xv.z * wvv.z + xv.w * wvv.w;
            }
        }
        #pragma unroll
        for (int b = 0; b < NB; b++) {
            #pragma unroll
            for (int off = 32; off; off >>= 1) acc[b] += __shfl_down(acc[b], off, 64);
        }
        if (lane == 0) {
            #pragma unroll
            for (int b = 0; b < NB; b++) part[wv][b] = acc[b];
        }
        __syncthreads();
        if (t < NB)
            y[t * DIM + o] = part[0][t] + part[1][t] + part[2][t] + part[3][t];
        __syncthreads();   // part[] reused next i
    }
    __threadfence();       // make y stores device-visible
    __syncthreads();
    if (t == 0)
        __hip_atomic_fetch_add(&cnt[B >> 6], 4, __ATOMIC_RELEASE,
                               __HIP_MEMORY_SCOPE_AGENT);

    // ================= consume: 4 tiles, all with ct = B>>6 ===================
    const int ct = B >> 6;            // column group [ct*256, +256)
    if (t == 0) {
        while (__hip_atomic_load(&cnt[ct], __ATOMIC_ACQUIRE,
                                 __HIP_MEMORY_SCOPE_AGENT) < 256)
            __builtin_amdgcn_s_sleep(8);
    }
    __syncthreads();
    __threadfence();       // invalidate caches so y reads are fresh

    const int c0 = seqlen[0];
    const int c1 = c0 + seqlen[1];
    const int c2 = c1 + seqlen[2];
    const int c3 = c2 + seqlen[3];
    const int c4 = c3 + seqlen[4];
    const int c5 = c4 + seqlen[5];
    const int c6 = c5 + seqlen[6];
    const float4* y4 = (const float4*)y;

    #pragma unroll
    for (int i = 0; i < 4; i++) {
        const int tl = B * 4 + i;     // tile id 0..4095
        const int rt = tl & 255;      // row group [rt*64, +64)
        // stage y[s][ct*64 .. +64) for all 8 sequences into LDS (8 KB)
        #pragma unroll
        for (int j = 0; j < 2; j++) {
            int idx = j * 256 + t;    // 0..511
            int s   = idx >> 6;
            int c4i = idx & 63;
            tile[s][c4i] = y4[s * (DIM / 4) + ct * 64 + c4i];
        }
        __syncthreads();
        // 64 rows x 64 float4 writes; each wave writes 1 KB contiguous
        #pragma unroll
        for (int j = 0; j < 16; j++) {
            int idx = j * 256 + t;    // 0..4095
            int rl  = idx >> 6;       // uniform per wave
            int c4i = idx & 63;
            int row = rt * 64 + rl;
            int s = (row >= c0) + (row >= c1) + (row >= c2) + (row >= c3)
                  + (row >= c4) + (row >= c5) + (row >= c6);
            out[(long)row * (DIM / 4) + ct * 64 + c4i] = tile[s][c4i];
        }
        __syncthreads();   // tile[] reused next i
    }
}

extern "C" void kernel_launch(void* const* d_in, const int* in_sizes, int n_in,
                              void* d_out, int out_size, void* d_ws, size_t ws_size,
                              hipStream_t stream) {
    const float* emb = (const float*)d_in[0];
    const float* wup = (const float*)d_in[1];
    const float* wdn = (const float*)d_in[2];
    const int* seqlen = (const int*)d_in[3];

    float* x   = (float*)d_ws;                 // 8*1024 f32 = 32 KB
    float* y   = x + NB * KVDIM;               // 8*4096 f32 = 128 KB
    int*   cnt = (int*)(y + NB * DIM);         // 16 ints

    k_up<<<NB * KVDIM / 4, 256, 0, stream>>>(emb, wup, x, cnt);
    k_dc<<<GRID2,          256, 0, stream>>>(x, wdn, y, cnt, seqlen,
                                             (float4*)d_out);
}

// Round 10
// 343.270 us; speedup vs baseline: 1.8803x; 1.8803x over previous
//
#include <hip/hip_runtime.h>

#define DIM   4096
#define KVDIM 1024   // n_kv_heads * head_dim
#define NB    8      // batch
#define TOTAL 16384
#define BCAST_BLOCKS 8192   // 2 rows per block

// x[b*KVDIM + j] = dot(emb[b,:], W_up[j,:])  -- one wave per (j,b), unrolled x16
__global__ __launch_bounds__(256)
void k_up(const float* __restrict__ emb, const float* __restrict__ wup,
          float* __restrict__ x) {
    int wid  = blockIdx.x * 4 + (threadIdx.x >> 6);
    int lane = threadIdx.x & 63;
    int j = wid >> 3;      // 0..1023 (b inner: 8 consecutive waves share one W_up row)
    int b = wid & 7;
    const float4* e = (const float4*)(emb + b * DIM);
    const float4* w = (const float4*)(wup + (long)j * DIM);
    float acc = 0.f;
    #pragma unroll
    for (int ii = 0; ii < 16; ii++) {
        int it = ii * 64 + lane;
        float4 ev = e[it], wv = w[it];
        acc += ev.x * wv.x + ev.y * wv.y + ev.z * wv.z + ev.w * wv.w;
    }
    #pragma unroll
    for (int off = 32; off; off >>= 1) acc += __shfl_down(acc, off, 64);
    if (lane == 0) x[b * KVDIM + j] = acc;
}

// y[b*DIM + o] = dot(val[b,:], W_down[o,:]),  val[b,k] = x[b,(k>>9)*128 + (k&127)]
// One o per block, K split across 4 waves. All 4 W_down loads hoisted up front
// (single HBM-latency exposure), then 32 L2-hot x loads + FMAs.
__global__ __launch_bounds__(256)
void k_down(const float* __restrict__ x, const float* __restrict__ wdn,
            float* __restrict__ y) {
    __shared__ float part[4][NB];
    int o    = blockIdx.x;            // 0..4095
    int wv   = threadIdx.x >> 6;      // K-quarter
    int lane = threadIdx.x & 63;
    const float4* w = (const float4*)(wdn + (long)o * DIM);

    // hoisted W_down loads: 4 float4 in flight before any use
    float4 wr[4];
    int kvi[4];
    #pragma unroll
    for (int ii = 0; ii < 4; ii++) {
        int it = wv * 256 + ii * 64 + lane;
        wr[ii] = w[it];
        int k0 = it * 4;
        kvi[ii] = ((k0 >> 9) << 7) + (k0 & 127);   // 16B-aligned gather index
    }

    float acc[NB];
    #pragma unroll
    for (int b = 0; b < NB; b++) acc[b] = 0.f;
    #pragma unroll
    for (int ii = 0; ii < 4; ii++) {
        float4 wvv = wr[ii];
        #pragma unroll
        for (int b = 0; b < NB; b++) {
            const float4 xv = *(const float4*)(x + b * KVDIM + kvi[ii]);
            acc[b] += xv.x * wvv.x + xv.y * wvv.y + xv.z * wvv.z + xv.w * wvv.w;
        }
    }
    #pragma unroll
    for (int b = 0; b < NB; b++) {
        #pragma unroll
        for (int off = 32; off; off >>= 1) acc[b] += __shfl_down(acc[b], off, 64);
    }
    if (lane == 0) {
        #pragma unroll
        for (int b = 0; b < NB; b++) part[wv][b] = acc[b];
    }
    __syncthreads();
    if (threadIdx.x < NB) {
        int b = threadIdx.x;
        y[b * DIM + o] = part[0][b] + part[1][b] + part[2][b] + part[3][b];
    }
}

// out[row,:] = y[seq_id(row),:]  -- 2 rows per block, plain float4 stores.
__global__ __launch_bounds__(256)
void k_bcast(const float* __restrict__ y, const int* __restrict__ seqlen,
             float4* __restrict__ out) {
    int c0 = seqlen[0];
    int c1 = c0 + seqlen[1];
    int c2 = c1 + seqlen[2];
    int c3 = c2 + seqlen[3];
    int c4 = c3 + seqlen[4];
    int c5 = c4 + seqlen[5];
    int c6 = c5 + seqlen[6];
    #pragma unroll
    for (int g = 0; g < TOTAL / BCAST_BLOCKS; g++) {
        int row = blockIdx.x + g * BCAST_BLOCKS;
        int s = (row >= c0) + (row >= c1) + (row >= c2) + (row >= c3)
              + (row >= c4) + (row >= c5) + (row >= c6);
        const float4* yr = (const float4*)(y + s * DIM);
        float4* orow = out + (long)row * (DIM / 4);
        #pragma unroll
        for (int c = threadIdx.x; c < DIM / 4; c += 256)
            orow[c] = yr[c];
    }
}

extern "C" void kernel_launch(void* const* d_in, const int* in_sizes, int n_in,
                              void* d_out, int out_size, void* d_ws, size_t ws_size,
                              hipStream_t stream) {
    const float* emb = (const float*)d_in[0];
    const float* wup = (const float*)d_in[1];
    const float* wdn = (const float*)d_in[2];
    const int* seqlen = (const int*)d_in[3];

    float* x = (float*)d_ws;           // 8*1024 fp32 = 32 KB
    float* y = x + NB * KVDIM;         // 8*4096 fp32 = 128 KB

    k_up   <<<NB * KVDIM / 4, 256, 0, stream>>>(emb, wup, x);
    k_down <<<DIM,            256, 0, stream>>>(x, wdn, y);
    k_bcast<<<BCAST_BLOCKS,   256, 0, stream>>>(y, seqlen, (float4*)d_out);
}